// Round 6
// baseline (1467.307 us; speedup 1.0000x reference)
//
#include <hip/hip_runtime.h>
#include <hip/hip_bf16.h>

// Problem constants (DAG_61246233641129)
#define IN_SIZE 1024
#define N_NODES 4224
#define TOTAL   5248   // IN_SIZE + N_NODES
#define BATCH   512
#define OUTSZ   128
#define NB      128    // node block size
#define NBLK    33     // N_NODES / NB

typedef __attribute__((ext_vector_type(8))) short short8;
typedef __attribute__((ext_vector_type(4))) float f32x4;

#define MFMA16 __builtin_amdgcn_mfma_f32_16x16x32_bf16

// fast tanh: tanh(x) = 1 - 2/(exp2(2x*log2e)+1)
__device__ __forceinline__ float fast_tanh(float x) {
  float e = __builtin_amdgcn_exp2f(x * 2.885390081777927f);
  return 1.0f - 2.0f * __builtin_amdgcn_rcpf(e + 1.0f);
}
__device__ __forceinline__ float fast_sigmoid(float x) {
  return __builtin_amdgcn_rcpf(1.0f + __builtin_amdgcn_exp2f(-x * 1.4426950408889634f));
}
__device__ __forceinline__ unsigned pack2(float a, float b) {
  __hip_bfloat162 h = __float22bfloat162_rn(float2{a, b});
  return *reinterpret_cast<unsigned*>(&h);
}
__device__ __forceinline__ uint4 cvtA_u4(const float* p) {
  float4 v0 = *(const float4*)p;
  float4 v1 = *(const float4*)(p + 4);
  uint4 u;
  u.x = pack2(v0.x, v0.y); u.y = pack2(v0.z, v0.w);
  u.z = pack2(v1.x, v1.y); u.w = pack2(v1.z, v1.w);
  return u;
}
__device__ __forceinline__ short8 cvtA(const float* p) {
  union { uint4 u; short8 s; } c; c.u = cvtA_u4(p); return c.s;
}
// A-operand: 16B fragment of recurrent weights, row j, recurrent offset koff.
// Wave pattern (rl,kh): 16 rows x 64B contiguous each -> fully-used cache lines.
template<bool WB>
__device__ __forceinline__ short8 loadA(const float* W, const ushort* Wb,
                                        int row, int koff) {
  if constexpr (WB) return *(const short8*)(Wb + (size_t)row * N_NODES + koff);
  else return cvtA(W + (size_t)row * TOTAL + IN_SIZE + koff);
}
// B-operand from swizzled LDS h buffer: local batch b (0..31), logical chunk cl (0..15)
__device__ __forceinline__ short8 ldsB(const ushort* hb, int b, int cl) {
  return *(const short8*)(hb + b * NB + ((cl ^ (b & 7)) << 3));
}

// ---------------- Gt[b][i] = bf16(x[b][i]), stride IN_SIZE ----------------
__global__ void conv_x(const float* __restrict__ x, ushort* __restrict__ Gt) {
  int idx = blockIdx.x * 256 + threadIdx.x;
  int b = idx >> 7, i8 = (idx & 127) * 8;
  *(uint4*)(Gt + (size_t)b * IN_SIZE + i8) = cvtA_u4(x + (size_t)b * IN_SIZE + i8);
}

// ---- Wb[j][i2] = bf16(W[j][IN+i2]) for i2 < (j/128)*128 (lower block-tri) ----
__global__ void wconv(const float* __restrict__ W, ushort* __restrict__ Wb) {
  int j = blockIdx.x;
  int lim = (j >> 7) << 7;
  const float* src = W + (size_t)j * TOTAL + IN_SIZE;
  ushort* dst = Wb + (size_t)j * N_NODES;
  for (int i8 = threadIdx.x * 8; i8 < lim; i8 += 256 * 8)
    *(uint4*)(dst + i8) = cvtA_u4(src + i8);
}

// ---- Wd[k][i][swz(j)] = W[k*NB+j][IN+k*NB+i] (solve-ready diag image) ----
__global__ void wdiag(const float* __restrict__ W, float* __restrict__ Wd) {
  __shared__ float tl[32][33];
  int k = blockIdx.x;
  int ti = blockIdx.y & 3, tj = blockIdx.y >> 2;
  int tx = threadIdx.x & 31, ty = threadIdx.x >> 5;
  int j0 = k * NB;
#pragma unroll
  for (int q = 0; q < 4; q++) {
    int jl = ty + q * 8;
    tl[jl][tx] = W[(size_t)(j0 + tj * 32 + jl) * TOTAL + IN_SIZE + j0 + ti * 32 + tx];
  }
  __syncthreads();
  int swz = (tj & 3) << 2;
#pragma unroll
  for (int q = 0; q < 4; q++) {
    int il = ty + q * 8;
    Wd[(size_t)k * NB * NB + (ti * 32 + il) * NB + ((tj * 32 + tx) ^ swz)] = tl[tx][il];
  }
}

// -------- init GEMM: C[j][b] = sum_{i<1024} W[j][i]*Gt[b][i] (proven) --------
__global__ void gemm_init(const float* __restrict__ W, const ushort* __restrict__ Gt,
                          float* __restrict__ C) {
  __shared__ uint4 Al[128][4];
  __shared__ uint4 Bl[128][4];
  int t = threadIdx.x;
  int jbase = blockIdx.x * 128, bbase = blockIdx.y * 128;
  int w = t >> 6, l = t & 63;
  int wm = w >> 1, wn = w & 1;
  int rl = l & 15, kh = l >> 4;
  int rdc = kh ^ ((rl >> 1) & 3);
  f32x4 acc[4][4];
#pragma unroll
  for (int m = 0; m < 4; m++)
#pragma unroll
    for (int n = 0; n < 4; n++) acc[m][n] = f32x4{0.f, 0.f, 0.f, 0.f};
  int srow = t >> 1, shalf = t & 1;
  int ssw = (srow >> 1) & 3;
  const float*  wa = W  + (size_t)(jbase + srow) * TOTAL + shalf * 16;
  const ushort* gb = Gt + (size_t)(bbase + srow) * IN_SIZE + shalf * 16;
  for (int kk = 0; kk < IN_SIZE; kk += 32) {
    uint4 p0 = cvtA_u4(wa + kk), p1 = cvtA_u4(wa + kk + 8);
    const uint4* q = (const uint4*)(gb + kk);
    uint4 q0 = q[0], q1 = q[1];
    __syncthreads();
    Al[srow][(shalf * 2) ^ ssw] = p0;
    Al[srow][(shalf * 2 + 1) ^ ssw] = p1;
    Bl[srow][(shalf * 2) ^ ssw] = q0;
    Bl[srow][(shalf * 2 + 1) ^ ssw] = q1;
    __syncthreads();
    short8 af[4], bf[4];
#pragma unroll
    for (int m = 0; m < 4; m++) af[m] = *(const short8*)&Al[wm * 64 + m * 16 + rl][rdc];
#pragma unroll
    for (int n = 0; n < 4; n++) bf[n] = *(const short8*)&Bl[wn * 64 + n * 16 + rl][rdc];
#pragma unroll
    for (int m = 0; m < 4; m++)
#pragma unroll
      for (int n = 0; n < 4; n++)
        acc[m][n] = MFMA16(af[m], bf[n], acc[m][n], 0, 0, 0);
  }
#pragma unroll
  for (int m = 0; m < 4; m++) {
    int jr = jbase + wm * 64 + m * 16 + kh * 4;
#pragma unroll
    for (int n = 0; n < 4; n++) {
      int bc = bbase + wn * 64 + n * 16 + rl;
      float* cp = C + (size_t)jr * BATCH + bc;
#pragma unroll
      for (int q2 = 0; q2 < 4; q2++) cp[(size_t)q2 * BATCH] = acc[m][n][q2];
    }
  }
}

// ---------------- zero-sync persistent solver ----------------
// 16 WGs x 1024 threads (1/CU); WG owns batches [wg*32, wg*32+32). No inter-WG
// communication. Per step k, 3 barriers:
//   A: waves 8-15 load C col k + MFMA-fold h_{k-1} -> Cl; waves 4-7 issue
//      next-diag-block prefetch loads.                                   [S1]
//   B: waves 0-3 serial-solve block k (setprio 1); waves 8-15 MFMA-fold
//      h_{k-1} into C cols k+1..32 (batched frag loads, deep ILP).       [S2]
//   C: waves 0-3 publish h (swizzled bf16 LDS) / final sigmoid;
//      waves 4-7 install prefetched diag block into Wt.                  [S3]
template<bool WB>
__global__ void __launch_bounds__(1024, 4)
persist(const float* __restrict__ W, const ushort* __restrict__ Wb,
        const float* __restrict__ Wd, float* __restrict__ C,
        float* __restrict__ out) {
  __shared__ float Wt[NB][NB];                  // 64 KB diag block (f32 exact)
  __shared__ float Cl[NB][33];                  // 16.9 KB col-k pre-activations
  __shared__ alignas(16) ushort Hl[2][32 * NB]; // 16 KB swizzled h (bf16), dbuf
  const int t = threadIdx.x;
  const int wave = t >> 6, l = t & 63, rl = l & 15, kh = l >> 4;
  const int b0 = blockIdx.x * 32;

  // prologue: Wt <- Wd[0]
#pragma unroll
  for (int q = 0; q < 4; q++)
    ((f32x4*)Wt)[q * 1024 + t] = ((const f32x4*)Wd)[q * 1024 + t];
  __syncthreads();

  f32x4 pf[16];

  for (int k = 0; k < NBLK; ++k) {
    const int j0 = k * NB;
    // ---------- phase A ----------
    if (wave >= 8) {
      const int m = wave - 8;
      const int jr = j0 + m * 16;
      f32x4 a0, a1;
      const float* cp = C + (size_t)(jr + kh * 4) * BATCH + b0 + rl;
#pragma unroll
      for (int qq = 0; qq < 4; qq++) {
        a0[qq] = cp[(size_t)qq * BATCH];
        a1[qq] = cp[(size_t)qq * BATCH + 16];
      }
      if (k > 0) {
        const ushort* hb = Hl[(k - 1) & 1];
        const int arow = jr + rl;
        const int koff = (k - 1) * NB + kh * 8;
#pragma unroll
        for (int it = 0; it < 4; ++it) {
          short8 av = loadA<WB>(W, Wb, arow, koff + it * 32);
          a0 = MFMA16(av, ldsB(hb, rl, it * 4 + kh), a0, 0, 0, 0);
          a1 = MFMA16(av, ldsB(hb, 16 + rl, it * 4 + kh), a1, 0, 0, 0);
        }
      }
#pragma unroll
      for (int qq = 0; qq < 4; qq++) {
        Cl[m * 16 + kh * 4 + qq][rl] = a0[qq];
        Cl[m * 16 + kh * 4 + qq][16 + rl] = a1[qq];
      }
    } else if (wave >= 4 && k < NBLK - 1) {
      const f32x4* src = (const f32x4*)(Wd + (size_t)(k + 1) * NB * NB);
      int base = t - 256;
#pragma unroll
      for (int q = 0; q < 16; q++) pf[q] = src[q * 256 + base];
    }
    __syncthreads(); // S1

    // ---------- phase B ----------
    float hown[16];
    if (wave < 4) {
      __builtin_amdgcn_s_setprio(1);
      int li = t & 7, g = t >> 3;
      float acc[16];
#pragma unroll
      for (int m = 0; m < 16; m++) acc[m] = Cl[li * 16 + m][g];
      for (int r = 0; r < 8; r++) {
#pragma unroll
        for (int jj = 0; jj < 16; jj++) {
          int i = r * 16 + jj;
          float sv = __shfl(acc[jj], r, 8);
          float h = fast_tanh(sv);
          if (li == r) hown[jj] = h;
          const float* wrow = &Wt[i][0];
#pragma unroll
          for (int cc = 0; cc < 4; cc++) {
            int col = li * 16 + cc * 4;
            int pc = col ^ (((col >> 5) & 3) << 2);
            float4 wv = *(const float4*)(wrow + pc);
            acc[cc * 4 + 0] += h * wv.x;
            acc[cc * 4 + 1] += h * wv.y;
            acc[cc * 4 + 2] += h * wv.z;
            acc[cc * 4 + 3] += h * wv.w;
          }
        }
      }
      __builtin_amdgcn_s_setprio(0);
    } else if (wave >= 8 && k > 0 && k < NBLK - 1) {
      // trailing fold: source k-1 into cols k+1..32 for own 32 batches
      const ushort* hb = Hl[(k - 1) & 1];
      short8 bfr[2][4];
#pragma unroll
      for (int it = 0; it < 4; ++it) {
        bfr[0][it] = ldsB(hb, rl, it * 4 + kh);
        bfr[1][it] = ldsB(hb, 16 + rl, it * 4 + kh);
      }
      const int koff = (k - 1) * NB + kh * 8;
      for (int c = k + 1 + (wave - 8); c < NBLK; c += 8) {
        const int jb = c * NB;
#pragma unroll
        for (int mh = 0; mh < 2; ++mh) {
          // batch all loads (16 A-frags + 32 C scalars) before the MFMA chain
          short8 afr[4][4];
#pragma unroll
          for (int m = 0; m < 4; m++)
#pragma unroll
            for (int it = 0; it < 4; ++it)
              afr[m][it] = loadA<WB>(W, Wb, jb + (mh * 4 + m) * 16 + rl,
                                     koff + it * 32);
          f32x4 acc2[4][2];
          float* cb = C + (size_t)(jb + mh * 64 + kh * 4) * BATCH + b0 + rl;
#pragma unroll
          for (int m = 0; m < 4; m++) {
            float* cp = cb + (size_t)(m * 16) * BATCH;
#pragma unroll
            for (int qq = 0; qq < 4; qq++) {
              acc2[m][0][qq] = cp[(size_t)qq * BATCH];
              acc2[m][1][qq] = cp[(size_t)qq * BATCH + 16];
            }
          }
#pragma unroll
          for (int it = 0; it < 4; ++it)
#pragma unroll
            for (int m = 0; m < 4; m++) {
              acc2[m][0] = MFMA16(afr[m][it], bfr[0][it], acc2[m][0], 0, 0, 0);
              acc2[m][1] = MFMA16(afr[m][it], bfr[1][it], acc2[m][1], 0, 0, 0);
            }
#pragma unroll
          for (int m = 0; m < 4; m++) {
            float* cp = cb + (size_t)(m * 16) * BATCH;
#pragma unroll
            for (int qq = 0; qq < 4; qq++) {
              cp[(size_t)qq * BATCH] = acc2[m][0][qq];
              cp[(size_t)qq * BATCH + 16] = acc2[m][1][qq];
            }
          }
        }
      }
    }
    __syncthreads(); // S2

    // ---------- phase C ----------
    if (wave < 4) {
      int li = t & 7, g = t >> 3, b = b0 + g;
      if (k < NBLK - 1) {
        uint4 o0, o1;
        o0.x = pack2(hown[0],  hown[1]);  o0.y = pack2(hown[2],  hown[3]);
        o0.z = pack2(hown[4],  hown[5]);  o0.w = pack2(hown[6],  hown[7]);
        o1.x = pack2(hown[8],  hown[9]);  o1.y = pack2(hown[10], hown[11]);
        o1.z = pack2(hown[12], hown[13]); o1.w = pack2(hown[14], hown[15]);
        ushort* hp = Hl[k & 1] + g * NB;
        *(uint4*)(hp + (((li * 2) ^ (g & 7)) << 3))     = o0;
        *(uint4*)(hp + (((li * 2 + 1) ^ (g & 7)) << 3)) = o1;
      } else {
        float* op = out + (size_t)b * OUTSZ + li * 16;
#pragma unroll
        for (int m = 0; m < 16; m++) op[m] = fast_sigmoid(hown[m]);
      }
    } else if (wave < 8 && k < NBLK - 1) {
      int base = t - 256;
#pragma unroll
      for (int q = 0; q < 16; q++) ((f32x4*)Wt)[q * 256 + base] = pf[q];
    }
    __syncthreads(); // S3
  }
}

extern "C" void kernel_launch(void* const* d_in, const int* in_sizes, int n_in,
                              void* d_out, int out_size, void* d_ws, size_t ws_size,
                              hipStream_t stream) {
  const float* x = (const float*)d_in[0];
  const float* W = (const float*)d_in[1];
  float* out = (float*)d_out;

  // ws carve: C (8.65 MB) | Wd (2.16 MB) | Gt (1.05 MB) | Wb (35.7 MB, optional)
  char* p = (char*)d_ws;
  float*  C  = (float*)p;   p += (size_t)N_NODES * BATCH * 4;
  float*  Wd = (float*)p;   p += (size_t)NBLK * NB * NB * 4;
  ushort* Gt = (ushort*)p;  p += (size_t)BATCH * IN_SIZE * 2;
  ushort* Wb = (ushort*)p;
  size_t need_wb = (size_t)(p - (char*)d_ws) + (size_t)N_NODES * N_NODES * 2;
  bool use_wb = ws_size >= need_wb;

  hipLaunchKernelGGL(conv_x, dim3(256), dim3(256), 0, stream, x, Gt);
  hipLaunchKernelGGL(wdiag, dim3(NBLK, 16), dim3(256), 0, stream, W, Wd);
  if (use_wb)
    hipLaunchKernelGGL(wconv, dim3(N_NODES), dim3(256), 0, stream, W, Wb);
  hipLaunchKernelGGL(gemm_init, dim3(NBLK, 4), dim3(256), 0, stream, W, Gt, C);
  if (use_wb)
    hipLaunchKernelGGL((persist<true>), dim3(16), dim3(1024), 0, stream,
                       W, Wb, Wd, C, out);
  else
    hipLaunchKernelGGL((persist<false>), dim3(16), dim3(1024), 0, stream,
                       W, Wb, Wd, C, out);
}